// Round 1
// 1792.860 us; speedup vs baseline: 1.6707x; 1.6707x over previous
//
#include <hip/hip_runtime.h>

// CAM module: per-segment channel attention.
//   X = segment flat buffer viewed as [C=256, n=65536]
//   E = X X^T  (Gram, 256x256, K=65536)
//   attn = softmax(rowmax(E) - E) == softmin(E)   (row-constant cancels)
//   out_flat = gamma * (attn @ X) + X   (flat indices align with feats)
//
// R1 changes vs baseline (2995 us, gram 2185 us):
//  - gram micro-tile interleaved by 32: b[j]=As[kk][tc+32*j] reads 32
//    consecutive words across the half-wave (conflict-free; was stride-8
//    -> 8-way conflict, SQ_LDS_BANK_CONFLICT=6.7e8). a-reads are half-wave
//    broadcasts (free).
//  - atomics removed: each WG stores a private 256KB partial Gram slab
//    (64MB ws, gated on ws_size with atomic fallback); softmin folds the
//    32-way chunk reduction. Baseline WRITE_SIZE was exactly 16.7M*32B --
//    every device-scope atomic forced an HBM writeback.

#define SEGS 8
#define CCH 256
#define NPTS 65536
#define KCHUNK 2048               // K per workgroup -> 8*32 = 256 WGs (1/CU)
#define NCHUNK (NPTS / KCHUNK)    // 32 partial slabs per segment
#define KTILE 32                  // K per LDS tile
#define JCHUNK 4096               // columns per block in apply kernel

// ---------------- zero workspace (atomic fallback path only) ----------------
__global__ void zero_ws_kernel(float* __restrict__ g, int n) {
    int i = blockIdx.x * blockDim.x + threadIdx.x;
    if (i < n) g[i] = 0.0f;
}

// ---------------- Gram: partial E for one (seg, kchunk) ----------------
// PARTIAL=true : plain stores to G[kc][seg][256][256]   (64MB ws)
// PARTIAL=false: atomicAdd into G[seg][256][256]        (2MB ws fallback)
template<bool PARTIAL>
__global__ __launch_bounds__(1024)
void gram_kernel(const float* __restrict__ feats, float* __restrict__ G) {
    const int seg = blockIdx.x / NCHUNK;
    const int kc  = blockIdx.x % NCHUNK;
    const float* __restrict__ X = feats + (size_t)seg * CCH * NPTS;
    const size_t k0 = (size_t)kc * KCHUNK;

    // A-tile == B-tile for a Gram matrix: stage once.
    // As[kk][r] = X[r][k0+kt+kk]; pad row to 257 words.
    // Store banks: addr = kk*257 + r -> bank (kk + r) % 32; the staging
    // pattern below covers each bank exactly twice per wave (free).
    __shared__ float As[KTILE][CCH + 1];

    const int t  = threadIdx.x;
    const int tr = t >> 5;     // 0..31
    const int tc = t & 31;     // 0..31

    float acc[8][8];
#pragma unroll
    for (int i = 0; i < 8; i++)
#pragma unroll
        for (int j = 0; j < 8; j++) acc[i][j] = 0.0f;

    for (int kt = 0; kt < KCHUNK; kt += KTILE) {
        // load 256x32 tile as 2048 float4: 2 per thread, 16B coalesced rows
#pragma unroll
        for (int l = 0; l < 2; l++) {
            int v  = l * 1024 + t;
            int r  = v >> 3;          // row 0..255
            int kq = (v & 7) * 4;     // k within tile: 0,4,...,28
            const float4 x4 = *(const float4*)(X + (size_t)r * NPTS + k0 + kt + kq);
            As[kq + 0][r] = x4.x;
            As[kq + 1][r] = x4.y;
            As[kq + 2][r] = x4.z;
            As[kq + 3][r] = x4.w;
        }
        __syncthreads();

        for (int kk = 0; kk < KTILE; kk++) {
            float a[8], b[8];
            // a: same address across each half-wave -> broadcast (free)
            // b: 32 consecutive words across half-wave -> all 32 banks (free)
#pragma unroll
            for (int i = 0; i < 8; i++) a[i] = As[kk][tr + 32 * i];
#pragma unroll
            for (int j = 0; j < 8; j++) b[j] = As[kk][tc + 32 * j];
#pragma unroll
            for (int i = 0; i < 8; i++)
#pragma unroll
                for (int j = 0; j < 8; j++) acc[i][j] += a[i] * b[j];
        }
        __syncthreads();
    }

    // thread (tr,tc) owns E[tr+32i][tc+32j]: consecutive tc lanes ->
    // 128B-coalesced stores.
    if (PARTIAL) {
        float* __restrict__ Gp = G + ((size_t)kc * SEGS + seg) * CCH * CCH;
#pragma unroll
        for (int i = 0; i < 8; i++)
#pragma unroll
            for (int j = 0; j < 8; j++)
                Gp[(size_t)(tr + 32 * i) * CCH + (tc + 32 * j)] = acc[i][j];
    } else {
        float* __restrict__ Gs = G + (size_t)seg * CCH * CCH;
#pragma unroll
        for (int i = 0; i < 8; i++)
#pragma unroll
            for (int j = 0; j < 8; j++)
                atomicAdd(&Gs[(size_t)(tr + 32 * i) * CCH + (tc + 32 * j)], acc[i][j]);
    }
}

// ---------------- softmin over each 256-wide row ----------------
// PARTIAL=true : sum 32 chunk slabs, write attn into the kc=0 slab
//               (in-place safe: each block reads only its own row slices,
//                writes only locations this block read).
// PARTIAL=false: in-place on the 2MB atomic buffer (as baseline).
template<bool PARTIAL>
__global__ __launch_bounds__(256)
void softmin_kernel(float* __restrict__ G) {
    const int row = blockIdx.x;                 // seg*256 + c
    const int t = threadIdx.x;

    float v;
    if (PARTIAL) {
        const int seg = row >> 8;
        const int c   = row & 255;
        v = 0.0f;
        for (int kc = 0; kc < NCHUNK; kc++)     // 32 coalesced 1KB reads
            v += G[((size_t)kc * SEGS + seg) * CCH * CCH + (size_t)c * CCH + t];
    } else {
        v = G[(size_t)row * CCH + t];
    }

    __shared__ float sm[4];

    // block min (wave64 shuffle + 4-wave LDS)
    float m = v;
#pragma unroll
    for (int off = 1; off < 64; off <<= 1) m = fminf(m, __shfl_xor(m, off, 64));
    if ((t & 63) == 0) sm[t >> 6] = m;
    __syncthreads();
    m = fminf(fminf(sm[0], sm[1]), fminf(sm[2], sm[3]));
    __syncthreads();

    float e = __expf(m - v);   // <= 1, underflows to 0 for huge gaps (matches ref)

    // block sum
    float s = e;
#pragma unroll
    for (int off = 1; off < 64; off <<= 1) s += __shfl_xor(s, off, 64);
    if ((t & 63) == 0) sm[t >> 6] = s;
    __syncthreads();
    s = sm[0] + sm[1] + sm[2] + sm[3];

    // attn lands at G[seg][c][*] in both modes (kc=0 slab has that layout)
    G[(size_t)row * CCH + t] = e / s;
}

// ---------------- out = gamma * (attn @ X) + X (flat residual) ----------------
__global__ __launch_bounds__(256)
void apply_kernel(const float* __restrict__ feats, const float* __restrict__ attn,
                  const float* __restrict__ gamma, float* __restrict__ out) {
    const int rowid = blockIdx.y;               // seg*256 + c
    const int seg = rowid >> 8;
    const int c   = rowid & 255;
    const float* __restrict__ X = feats + (size_t)seg * CCH * NPTS;
    const float* __restrict__ A = attn + (size_t)rowid * CCH;

    __shared__ float w[CCH];
    const int t = threadIdx.x;
    w[t] = A[t];
    __syncthreads();

    const float g = *gamma;
    const size_t j0 = (size_t)blockIdx.x * JCHUNK;

    float4 acc[4];
#pragma unroll
    for (int u = 0; u < 4; u++) acc[u] = make_float4(0.f, 0.f, 0.f, 0.f);

    // attn is near-one-hot: skip negligible weights (wave-uniform branch).
    for (int d = 0; d < CCH; d++) {
        float wd = w[d];
        if (wd > 1e-8f) {
            const float4* __restrict__ Xd = (const float4*)(X + (size_t)d * NPTS + j0);
#pragma unroll
            for (int u = 0; u < 4; u++) {
                float4 xv = Xd[u * 256 + t];
                acc[u].x += wd * xv.x; acc[u].y += wd * xv.y;
                acc[u].z += wd * xv.z; acc[u].w += wd * xv.w;
            }
        }
    }

    const float4* __restrict__ Xc = (const float4*)(X + (size_t)c * NPTS + j0);
    float4* __restrict__ O = (float4*)(out + (size_t)seg * CCH * NPTS + (size_t)c * NPTS + j0);
#pragma unroll
    for (int u = 0; u < 4; u++) {
        float4 xv = Xc[u * 256 + t];
        float4 r;
        r.x = g * acc[u].x + xv.x;
        r.y = g * acc[u].y + xv.y;
        r.z = g * acc[u].z + xv.z;
        r.w = g * acc[u].w + xv.w;
        O[u * 256 + t] = r;
    }
}

extern "C" void kernel_launch(void* const* d_in, const int* in_sizes, int n_in,
                              void* d_out, int out_size, void* d_ws, size_t ws_size,
                              hipStream_t stream) {
    const float* feats = (const float*)d_in[0];
    const float* gamma = (const float*)d_in[1];
    float* out = (float*)d_out;
    float* G   = (float*)d_ws;

    const size_t partial_bytes = (size_t)NCHUNK * SEGS * CCH * CCH * sizeof(float); // 64MB

    if (ws_size >= partial_bytes) {
        // partial-slab path: no atomics, no zero pass
        gram_kernel<true><<<SEGS * NCHUNK, 1024, 0, stream>>>(feats, G);
        softmin_kernel<true><<<SEGS * CCH, 256, 0, stream>>>(G);
        apply_kernel<<<dim3(NPTS / JCHUNK, SEGS * CCH), 256, 0, stream>>>(feats, G, gamma, out);
    } else {
        // fallback: baseline atomic accumulation into 2MB
        const int gElems = SEGS * CCH * CCH;
        zero_ws_kernel<<<(gElems + 255) / 256, 256, 0, stream>>>(G, gElems);
        gram_kernel<false><<<SEGS * NCHUNK, 1024, 0, stream>>>(feats, G);
        softmin_kernel<false><<<SEGS * CCH, 256, 0, stream>>>(G);
        apply_kernel<<<dim3(NPTS / JCHUNK, SEGS * CCH), 256, 0, stream>>>(feats, G, gamma, out);
    }
}